// Round 9
// baseline (251.791 us; speedup 1.0000x reference)
//
#include <hip/hip_runtime.h>

// ---------------------------------------------------------------------------
// GNN action-value net, MI355X. Round 9: 2 graphs per block (software
// pipelining at graph level).
//  * 512 blocks x 256 thr; every phase runs graph A then graph B between the
//    same barriers -> per-graph barrier cost halves, in-wave ILP doubles
//    (two independent dependency chains), 2x memory-level parallelism in P0.
//  * LDS 76.8KB -> 2 blocks/CU; 512-block grid exactly co-resident.
//  * prep unchanged (44 blocks).
// Fragment maps (verified r5-r8): A[m][k]: m=lane&15, k=(lane>>4)*8+j;
// B[k][n]: n=lane&15, k=(lane>>4)*8+j; C/D: col=lane&15, row=(lane>>4)*4+reg.
// ---------------------------------------------------------------------------

#define NPG 64
#define EPG 1024
#define NEPG 256
#define B_GR 1024
#define E_TOT 1048576
#define EMB 64
#define HID 128
#define NOUT 101
#define OUT_PG 6721            // 1 + 64*101 + 256

typedef __attribute__((ext_vector_type(8))) short bf16x8;
typedef __attribute__((ext_vector_type(4))) float f32x4;
typedef unsigned short ushort_t;

__device__ ushort_t g_c1w[EMB*HID];      // frag-packed bf16 (K=64)
__device__ ushort_t g_c2w[HID*HID];      // frag-packed bf16
__device__ ushort_t g_nw1[HID*HID];
__device__ ushort_t g_ew1[HID*HID];
__device__ ushort_t g_nw2[HID*112];      // N padded 101 -> 112
__device__ float    g_sw1t[HID*HID];     // s_w1 transposed, f32
__device__ float    g_he1[4], g_he2[4];

__device__ __forceinline__ ushort_t f2bf(float f) {
  unsigned u = __float_as_uint(f);
  return (ushort_t)((u + 0x7fffu + ((u >> 16) & 1u)) >> 16);
}
__device__ __forceinline__ float bf2f(ushort_t h) {
  return __uint_as_float(((unsigned)h) << 16);
}

// ---------------------------------------------------------------------------
// prep: 44 blocks. b0: logit-constant dots. b1-4: c1w. b5-12: c2w.
// b13-20: nw1. b21-28: ew1. b29-35: nw2. b36-43: sw1t.
__global__ void prep_kernel(
    const float* __restrict__ edge_tab,
    const float* __restrict__ c1_w,  const float* __restrict__ c1_we,
    const float* __restrict__ c1_ae,
    const float* __restrict__ c2_w,  const float* __restrict__ c2_we,
    const float* __restrict__ c2_ae,
    const float* __restrict__ s_w1,  const float* __restrict__ n_w1,
    const float* __restrict__ n_w2,  const float* __restrict__ e_w1)
{
  const int b = blockIdx.x, tid = threadIdx.x;
  if (b == 0) {
    __shared__ float v1[EMB], v2[EMB];
    if (tid < EMB) {
      float a = 0.f, d = 0.f;
      for (int j = 0; j < HID; ++j) {
        a = fmaf(c1_we[tid*HID + j], c1_ae[j], a);
        d = fmaf(c2_we[tid*HID + j], c2_ae[j], d);
      }
      v1[tid] = a; v2[tid] = d;
    }
    __syncthreads();
    if (tid < 4) {
      float a = 0.f, d = 0.f;
      for (int k = 0; k < EMB; ++k) {
        const float ev = edge_tab[tid*EMB + k];
        a = fmaf(ev, v1[k], a); d = fmaf(ev, v2[k], d);
      }
      g_he1[tid] = a; g_he2[tid] = d;
    }
    return;
  }
  if (b <= 4) {
    const int base = (b - 1) * 2048 + tid;
    #pragma unroll
    for (int it = 0; it < 8; ++it) {
      const int idx = base + it*256;
      const int j = idx & 7, l = (idx >> 3) & 63, r2 = idx >> 9;
      const int ks = r2 & 1, ct = r2 >> 1;
      const int row = ks*32 + (l >> 4)*8 + j;
      const int col = ct*16 + (l & 15);
      g_c1w[idx] = f2bf(c1_w[row*HID + col]);
    }
    return;
  }
  if (b <= 28) {
    const int grp = (b - 5) >> 3;
    const int chunk = (b - 5) & 7;
    const float* W = (grp == 0) ? c2_w : (grp == 1) ? n_w1 : e_w1;
    ushort_t* G = (grp == 0) ? g_c2w : (grp == 1) ? g_nw1 : g_ew1;
    const int base = chunk * 2048 + tid;
    #pragma unroll
    for (int it = 0; it < 8; ++it) {
      const int idx = base + it*256;
      const int j = idx & 7, l = (idx >> 3) & 63, r2 = idx >> 9;
      const int ks = r2 & 3, ct = r2 >> 2;
      const int row = ks*32 + (l >> 4)*8 + j;
      const int col = ct*16 + (l & 15);
      G[idx] = f2bf(W[row*HID + col]);
    }
    return;
  }
  if (b <= 35) {
    const int base = (b - 29) * 2048 + tid;
    #pragma unroll
    for (int it = 0; it < 8; ++it) {
      const int idx = base + it*256;
      const int j = idx & 7, l = (idx >> 3) & 63, r2 = idx >> 9;
      const int ks = r2 & 3, ct = r2 >> 2;
      const int row = ks*32 + (l >> 4)*8 + j;
      const int col = ct*16 + (l & 15);
      g_nw2[idx] = (col < NOUT) ? f2bf(n_w2[row*NOUT + col]) : (ushort_t)0;
    }
    return;
  }
  {
    const int base = (b - 36) * 2048 + tid;
    #pragma unroll
    for (int it = 0; it < 8; ++it) {
      const int idx = base + it*256;
      g_sw1t[idx] = s_w1[(idx & 127)*HID + (idx >> 7)];
    }
  }
}

// ---------------------------------------------------------------------------
// Per-graph LDS region (37888B, 16-aligned); 2 regions + shared ebw/hc.
#define S_HC   0        // 128x72 ushort col-major; reused as a1b 64x136 rows
#define S_R    18432    // overlay: Pf 64x64 f32 (16384) / Hr 64x136 us (17408)
#define S_PART 35840    // 256 f32 (stop partials)
#define S_NS   36864    // 64 f32
#define S_ND   37120    // 64 f32
#define S_GP   37376    // 128 f32
#define S_G    37888
#define S_EBW  (2*S_G)           // 256 f32 shared: e_b1 | e_w2
#define S_HCC  (S_EBW + 1024)    // 8 f32 shared
#define S_TOT  (S_HCC + 32)      // 76832

__global__ __launch_bounds__(256, 2) void graph_kernel(
    const float* __restrict__ node_tab,
    const float* __restrict__ c1_as, const float* __restrict__ c1_ad,
    const float* __restrict__ c1_b,
    const float* __restrict__ c2_as, const float* __restrict__ c2_ad,
    const float* __restrict__ c2_b,
    const float* __restrict__ s_b1,  const float* __restrict__ s_w2,
    const float* __restrict__ s_b2,
    const float* __restrict__ n_b1,  const float* __restrict__ n_b2,
    const float* __restrict__ e_b1,  const float* __restrict__ e_w2,
    const float* __restrict__ e_b2,
    const int* __restrict__ x,  const int* __restrict__ ei,
    const int* __restrict__ ea, const int* __restrict__ nedg,
    float* __restrict__ out)
{
  const int tid = threadIdx.x;
  const int g0 = blockIdx.x * 2;
  const int lane = tid & 63;
  const int wv = tid >> 6;
  const int qd = lane >> 4;
  const int cl = lane & 15;
  const int rb = wv * 16;

  __shared__ __align__(16) char smem[S_TOT];
  float* ebw = (float*)(smem + S_EBW);
  float* hc  = (float*)(smem + S_HCC);
  ushort_t* Hc[2]; float* Pf[2]; ushort_t* Hr[2]; float* part[2];
  float* ns[2]; float* nd[2]; float* gp[2];
  #pragma unroll
  for (int g = 0; g < 2; ++g) {
    char* base = smem + g*S_G;
    Hc[g] = (ushort_t*)(base + S_HC);
    Pf[g] = (float*)   (base + S_R);
    Hr[g] = (ushort_t*)(base + S_R);
    part[g] = (float*) (base + S_PART);
    ns[g] = (float*)   (base + S_NS);
    nd[g] = (float*)   (base + S_ND);
    gp[g] = (float*)   (base + S_GP);
  }

  unsigned er[2][4];
  int2 prr[2];
  bf16x8 ea0[2], ea1[2], pa0[2], pa1[2];
  float inv4[2][4];
  bf16x8 h1f[2][4], h2f[2][4];

  // ---- P0: edge regs, pair regs, emb frags, zero Pf/gp, consts ----
  #pragma unroll
  for (int g = 0; g < 2; ++g) {
    const int gg = g0 + g, nbg = gg * NPG;
    #pragma unroll
    for (int i = 0; i < 4; ++i) {
      const int k = tid + 256*i;
      const int s = ei[gg*EPG + k] - nbg;
      const int d = ei[E_TOT + gg*EPG + k] - nbg;
      const int t = ea[gg*EPG + k];
      er[g][i] = (unsigned)(s | (d << 6) | (t << 12));
    }
    prr[g] = *(const int2*)(nedg + 2*(gg*NEPG + tid));
    const int cat = x[nbg + rb + cl];
    const float* src = node_tab + cat*EMB;
    const float4 v0 = *(const float4*)(src + qd*8);
    const float4 v1 = *(const float4*)(src + qd*8 + 4);
    const float4 v2 = *(const float4*)(src + 32 + qd*8);
    const float4 v3 = *(const float4*)(src + 36 + qd*8);
    ea0[g][0]=f2bf(v0.x); ea0[g][1]=f2bf(v0.y); ea0[g][2]=f2bf(v0.z); ea0[g][3]=f2bf(v0.w);
    ea0[g][4]=f2bf(v1.x); ea0[g][5]=f2bf(v1.y); ea0[g][6]=f2bf(v1.z); ea0[g][7]=f2bf(v1.w);
    ea1[g][0]=f2bf(v2.x); ea1[g][1]=f2bf(v2.y); ea1[g][2]=f2bf(v2.z); ea1[g][3]=f2bf(v2.w);
    ea1[g][4]=f2bf(v3.x); ea1[g][5]=f2bf(v3.y); ea1[g][6]=f2bf(v3.z); ea1[g][7]=f2bf(v3.w);
    float4* pz = (float4*)Pf[g];
    #pragma unroll
    for (int j = 0; j < 4; ++j) pz[tid + j*256] = make_float4(0.f,0.f,0.f,0.f);
    if (tid < 128) gp[g][tid] = 0.f;
  }
  ebw[tid] = (tid < 128) ? e_b1[tid] : e_w2[tid - 128];
  if (tid < 8) hc[tid] = (tid < 4) ? g_he1[tid] : g_he2[tid-4];

  // ---- P2: h1pre = emb @ c1_w -> Hc col-major + ns/nd ----
  #pragma unroll
  for (int g = 0; g < 2; ++g) {
    float pns[4] = {0.f,0.f,0.f,0.f}, pnd[4] = {0.f,0.f,0.f,0.f};
    #pragma unroll
    for (int ct = 0; ct < 8; ++ct) {
      f32x4 acc = {0.f, 0.f, 0.f, 0.f};
      const bf16x8 b0 = *(const bf16x8*)(g_c1w + ((ct*2+0)*64 + lane)*8);
      const bf16x8 b1 = *(const bf16x8*)(g_c1w + ((ct*2+1)*64 + lane)*8);
      acc = __builtin_amdgcn_mfma_f32_16x16x32_bf16(ea0[g], b0, acc, 0, 0, 0);
      acc = __builtin_amdgcn_mfma_f32_16x16x32_bf16(ea1[g], b1, acc, 0, 0, 0);
      const int n = ct*16 + cl;
      const float asv = c1_as[n], adv = c1_ad[n];
      #pragma unroll
      for (int r = 0; r < 4; ++r) {
        const float v = acc[r];
        Hc[g][n*72 + (rb + qd*4 + r)] = f2bf(v);
        pns[r] = fmaf(v, asv, pns[r]);
        pnd[r] = fmaf(v, adv, pnd[r]);
      }
    }
    #pragma unroll
    for (int r = 0; r < 4; ++r) {
      #pragma unroll
      for (int off = 1; off < 16; off <<= 1) {
        pns[r] += __shfl_xor(pns[r], off, 64);
        pnd[r] += __shfl_xor(pnd[r], off, 64);
      }
    }
    if (cl == 0) {
      #pragma unroll
      for (int r = 0; r < 4; ++r) { ns[g][rb+qd*4+r] = pns[r]; nd[g][rb+qd*4+r] = pnd[r]; }
    }
  }
  __syncthreads();                                        // B1

  // ---- edge pass 1 ----
  #pragma unroll
  for (int g = 0; g < 2; ++g) {
    #pragma unroll
    for (int i = 0; i < 4; ++i) {
      const unsigned tp = er[g][i];
      const int s = tp & 63, d = (tp >> 6) & 63, t = tp >> 12;
      float l = ns[g][s] + nd[g][d] + hc[t];
      l = (l > 0.f) ? l : 0.2f * l;
      atomicAdd(&Pf[g][d*64 + s], __expf(l));
    }
  }
  __syncthreads();                                        // B2

  // ---- agg1 preload: P frags (f32->bf16 in-reg) + den rowsum ----
  #pragma unroll
  for (int g = 0; g < 2; ++g) {
    const float* pr = Pf[g] + (rb + cl)*64;
    const float4 v0 = *(const float4*)(pr + qd*8);
    const float4 v1 = *(const float4*)(pr + qd*8 + 4);
    const float4 v2 = *(const float4*)(pr + 32 + qd*8);
    const float4 v3 = *(const float4*)(pr + 36 + qd*8);
    pa0[g][0]=f2bf(v0.x); pa0[g][1]=f2bf(v0.y); pa0[g][2]=f2bf(v0.z); pa0[g][3]=f2bf(v0.w);
    pa0[g][4]=f2bf(v1.x); pa0[g][5]=f2bf(v1.y); pa0[g][6]=f2bf(v1.z); pa0[g][7]=f2bf(v1.w);
    pa1[g][0]=f2bf(v2.x); pa1[g][1]=f2bf(v2.y); pa1[g][2]=f2bf(v2.z); pa1[g][3]=f2bf(v2.w);
    pa1[g][4]=f2bf(v3.x); pa1[g][5]=f2bf(v3.y); pa1[g][6]=f2bf(v3.z); pa1[g][7]=f2bf(v3.w);
    float den = v0.x+v0.y+v0.z+v0.w + v1.x+v1.y+v1.z+v1.w
              + v2.x+v2.y+v2.z+v2.w + v3.x+v3.y+v3.z+v3.w;
    den += __shfl_xor(den, 16, 64);
    den += __shfl_xor(den, 32, 64);
    #pragma unroll
    for (int r = 0; r < 4; ++r)
      inv4[g][r] = 1.f / (__shfl(den, qd*4 + r, 64) + 1e-16f);
  }
  __syncthreads();                                        // B3

  // ---- agg1: h1 = relu(inv*(P@h1pre) + c1_b) -> Hr; preload h1f ----
  #pragma unroll
  for (int g = 0; g < 2; ++g) {
    #pragma unroll
    for (int ct = 0; ct < 8; ++ct) {
      f32x4 acc = {0.f, 0.f, 0.f, 0.f};
      const bf16x8 b0 = *(const bf16x8*)(Hc[g] + (ct*16+cl)*72 + qd*8);
      const bf16x8 b1 = *(const bf16x8*)(Hc[g] + (ct*16+cl)*72 + 32 + qd*8);
      acc = __builtin_amdgcn_mfma_f32_16x16x32_bf16(pa0[g], b0, acc, 0, 0, 0);
      acc = __builtin_amdgcn_mfma_f32_16x16x32_bf16(pa1[g], b1, acc, 0, 0, 0);
      const int n = ct*16 + cl;
      const float bias = c1_b[n];
      #pragma unroll
      for (int r = 0; r < 4; ++r)
        Hr[g][(rb + qd*4 + r)*136 + n] = f2bf(fmaxf(fmaf(acc[r], inv4[g][r], bias), 0.f));
    }
    #pragma unroll
    for (int ks = 0; ks < 4; ++ks)
      h1f[g][ks] = *(const bf16x8*)(Hr[g] + (rb+cl)*136 + ks*32 + qd*8);
  }
  __syncthreads();                                        // B4

  // ---- P7: h2pre = h1 @ c2_w -> Hc + ns/nd; zero Pf ----
  #pragma unroll
  for (int g = 0; g < 2; ++g) {
    float4* pz = (float4*)Pf[g];
    #pragma unroll
    for (int j = 0; j < 4; ++j) pz[tid + j*256] = make_float4(0.f,0.f,0.f,0.f);
    float pns[4] = {0.f,0.f,0.f,0.f}, pnd[4] = {0.f,0.f,0.f,0.f};
    #pragma unroll
    for (int ct = 0; ct < 8; ++ct) {
      f32x4 acc = {0.f, 0.f, 0.f, 0.f};
      #pragma unroll
      for (int ks = 0; ks < 4; ++ks) {
        const bf16x8 b = *(const bf16x8*)(g_c2w + ((ct*4+ks)*64 + lane)*8);
        acc = __builtin_amdgcn_mfma_f32_16x16x32_bf16(h1f[g][ks], b, acc, 0, 0, 0);
      }
      const int n = ct*16 + cl;
      const float asv = c2_as[n], adv = c2_ad[n];
      #pragma unroll
      for (int r = 0; r < 4; ++r) {
        const float v = acc[r];
        Hc[g][n*72 + (rb + qd*4 + r)] = f2bf(v);
        pns[r] = fmaf(v, asv, pns[r]);
        pnd[r] = fmaf(v, adv, pnd[r]);
      }
    }
    #pragma unroll
    for (int r = 0; r < 4; ++r) {
      #pragma unroll
      for (int off = 1; off < 16; off <<= 1) {
        pns[r] += __shfl_xor(pns[r], off, 64);
        pnd[r] += __shfl_xor(pnd[r], off, 64);
      }
    }
    if (cl == 0) {
      #pragma unroll
      for (int r = 0; r < 4; ++r) { ns[g][rb+qd*4+r] = pns[r]; nd[g][rb+qd*4+r] = pnd[r]; }
    }
  }
  __syncthreads();                                        // B5

  // ---- edge pass 2 ----
  #pragma unroll
  for (int g = 0; g < 2; ++g) {
    #pragma unroll
    for (int i = 0; i < 4; ++i) {
      const unsigned tp = er[g][i];
      const int s = tp & 63, d = (tp >> 6) & 63, t = tp >> 12;
      float l = ns[g][s] + nd[g][d] + hc[4 + t];
      l = (l > 0.f) ? l : 0.2f * l;
      atomicAdd(&Pf[g][d*64 + s], __expf(l));
    }
  }
  __syncthreads();                                        // B6

  // ---- agg2 preload ----
  #pragma unroll
  for (int g = 0; g < 2; ++g) {
    const float* pr = Pf[g] + (rb + cl)*64;
    const float4 v0 = *(const float4*)(pr + qd*8);
    const float4 v1 = *(const float4*)(pr + qd*8 + 4);
    const float4 v2 = *(const float4*)(pr + 32 + qd*8);
    const float4 v3 = *(const float4*)(pr + 36 + qd*8);
    pa0[g][0]=f2bf(v0.x); pa0[g][1]=f2bf(v0.y); pa0[g][2]=f2bf(v0.z); pa0[g][3]=f2bf(v0.w);
    pa0[g][4]=f2bf(v1.x); pa0[g][5]=f2bf(v1.y); pa0[g][6]=f2bf(v1.z); pa0[g][7]=f2bf(v1.w);
    pa1[g][0]=f2bf(v2.x); pa1[g][1]=f2bf(v2.y); pa1[g][2]=f2bf(v2.z); pa1[g][3]=f2bf(v2.w);
    pa1[g][4]=f2bf(v3.x); pa1[g][5]=f2bf(v3.y); pa1[g][6]=f2bf(v3.z); pa1[g][7]=f2bf(v3.w);
    float den = v0.x+v0.y+v0.z+v0.w + v1.x+v1.y+v1.z+v1.w
              + v2.x+v2.y+v2.z+v2.w + v3.x+v3.y+v3.z+v3.w;
    den += __shfl_xor(den, 16, 64);
    den += __shfl_xor(den, 32, 64);
    #pragma unroll
    for (int r = 0; r < 4; ++r)
      inv4[g][r] = 1.f / (__shfl(den, qd*4 + r, 64) + 1e-16f);
  }
  __syncthreads();                                        // B7

  // ---- agg2: h2 = inv*(P@h2pre) + c2_b -> Hr + pooling ----
  #pragma unroll
  for (int g = 0; g < 2; ++g) {
    #pragma unroll
    for (int ct = 0; ct < 8; ++ct) {
      f32x4 acc = {0.f, 0.f, 0.f, 0.f};
      const bf16x8 b0 = *(const bf16x8*)(Hc[g] + (ct*16+cl)*72 + qd*8);
      const bf16x8 b1 = *(const bf16x8*)(Hc[g] + (ct*16+cl)*72 + 32 + qd*8);
      acc = __builtin_amdgcn_mfma_f32_16x16x32_bf16(pa0[g], b0, acc, 0, 0, 0);
      acc = __builtin_amdgcn_mfma_f32_16x16x32_bf16(pa1[g], b1, acc, 0, 0, 0);
      const int n = ct*16 + cl;
      const float bias = c2_b[n];
      float colsum = 0.f;
      #pragma unroll
      for (int r = 0; r < 4; ++r) {
        const float v = fmaf(acc[r], inv4[g][r], bias);
        Hr[g][(rb + qd*4 + r)*136 + n] = f2bf(v);
        colsum += v;
      }
      colsum += __shfl_xor(colsum, 16, 64);
      colsum += __shfl_xor(colsum, 32, 64);
      if (qd == 0) atomicAdd(&gp[g][n], colsum);
    }
  }
  __syncthreads();                                        // B8

  // ---- stop head partials ----
  #pragma unroll
  for (int g = 0; g < 2; ++g) {
    const int j = tid & 127, half = tid >> 7;
    const float* wr = g_sw1t + j*HID + half*64;
    const float* gr = gp[g] + half*64;
    float p = 0.f;
    #pragma unroll
    for (int q = 0; q < 16; ++q) {
      const float4 w = ((const float4*)wr)[q];
      const float4 gv = ((const float4*)gr)[q];
      p = fmaf(w.x, gv.x, p); p = fmaf(w.y, gv.y, p);
      p = fmaf(w.z, gv.z, p); p = fmaf(w.w, gv.w, p);
    }
    part[g][tid] = p;
  }
  __syncthreads();                                        // B9

  // ---- post: stop reduce, fused addnode/addedge staging, addnode head ----
  #pragma unroll
  for (int g = 0; g < 2; ++g) {
    const int gg = g0 + g;
    if (tid < 64) {
      const float z0 = fmaxf(part[g][tid] + part[g][tid+128] + s_b1[tid], 0.f);
      const float z1 = fmaxf(part[g][tid+64] + part[g][tid+192] + s_b1[tid+64], 0.f);
      float p = fmaf(z0, s_w2[tid], z1 * s_w2[tid+64]);
      #pragma unroll
      for (int off = 32; off > 0; off >>= 1) p += __shfl_down(p, off, 64);
      if (tid == 0) out[(size_t)gg*OUT_PG] = p + s_b2[0];
    }
    #pragma unroll
    for (int ks = 0; ks < 4; ++ks)
      h2f[g][ks] = *(const bf16x8*)(Hr[g] + (rb+cl)*136 + ks*32 + qd*8);
    // fused: a1 = relu(h2@n_w1+n_b1) -> a1b(Hc); u = h2@e_w1 -> Hr (own rows)
    #pragma unroll
    for (int ct = 0; ct < 8; ++ct) {
      f32x4 an = {0.f, 0.f, 0.f, 0.f};
      f32x4 ae2 = {0.f, 0.f, 0.f, 0.f};
      #pragma unroll
      for (int ks = 0; ks < 4; ++ks) {
        const bf16x8 bn = *(const bf16x8*)(g_nw1 + ((ct*4+ks)*64 + lane)*8);
        const bf16x8 be = *(const bf16x8*)(g_ew1 + ((ct*4+ks)*64 + lane)*8);
        an  = __builtin_amdgcn_mfma_f32_16x16x32_bf16(h2f[g][ks], bn, an, 0, 0, 0);
        ae2 = __builtin_amdgcn_mfma_f32_16x16x32_bf16(h2f[g][ks], be, ae2, 0, 0, 0);
      }
      const int n = ct*16 + cl;
      const float bias = n_b1[n];
      #pragma unroll
      for (int r = 0; r < 4; ++r) {
        Hc[g][(rb + qd*4 + r)*136 + n] = f2bf(fmaxf(an[r] + bias, 0.f));
        Hr[g][(rb + qd*4 + r)*136 + n] = f2bf(ae2[r]);
      }
    }
    // addnode head: out = a1 @ n_w2p + n_b2 (own-wave a1b rows)
    bf16x8 af[4];
    #pragma unroll
    for (int ks = 0; ks < 4; ++ks)
      af[ks] = *(const bf16x8*)(Hc[g] + (rb+cl)*136 + ks*32 + qd*8);
    float* ob = out + (size_t)gg*OUT_PG + 1;
    #pragma unroll
    for (int ct = 0; ct < 7; ++ct) {
      f32x4 acc = {0.f, 0.f, 0.f, 0.f};
      #pragma unroll
      for (int ks = 0; ks < 4; ++ks) {
        const bf16x8 b = *(const bf16x8*)(g_nw2 + ((ct*4+ks)*64 + lane)*8);
        acc = __builtin_amdgcn_mfma_f32_16x16x32_bf16(af[ks], b, acc, 0, 0, 0);
      }
      const int o = ct*16 + cl;
      if (o < NOUT) {
        const float b2 = n_b2[o];
        #pragma unroll
        for (int r = 0; r < 4; ++r)
          ob[(size_t)(rb + qd*4 + r)*NOUT + o] = acc[r] + b2;
      }
    }
  }
  __syncthreads();                                        // B10

  // ---- addedge pairs (u in Hr region) ----
  #pragma unroll
  for (int g = 0; g < 2; ++g) {
    const int gg = g0 + g, nbg = gg * NPG;
    const ushort_t* ui = Hr[g] + (prr[g].x - nbg)*136;
    const ushort_t* uj = Hr[g] + (prr[g].y - nbg)*136;
    float ssum = 0.f;
    #pragma unroll
    for (int q8 = 0; q8 < 16; ++q8) {
      const bf16x8 va = *(const bf16x8*)(ui + q8*8);
      const bf16x8 vb = *(const bf16x8*)(uj + q8*8);
      #pragma unroll
      for (int j = 0; j < 8; ++j) {
        const int c = q8*8 + j;
        float v = bf2f((ushort_t)va[j]) + bf2f((ushort_t)vb[j]) + ebw[c];
        v = fmaxf(v, 0.f);
        ssum = fmaf(v, ebw[128 + c], ssum);
      }
    }
    out[(size_t)gg*OUT_PG + 1 + NPG*NOUT + tid] = ssum + e_b2[0];
  }
}

// ---------------------------------------------------------------------------
extern "C" void kernel_launch(void* const* d_in, const int* in_sizes, int n_in,
                              void* d_out, int out_size, void* d_ws, size_t ws_size,
                              hipStream_t stream) {
  const float* node_tab = (const float*)d_in[0];
  const float* edge_tab = (const float*)d_in[1];
  const float* c1_w  = (const float*)d_in[2];
  const float* c1_we = (const float*)d_in[3];
  const float* c1_as = (const float*)d_in[4];
  const float* c1_ad = (const float*)d_in[5];
  const float* c1_ae = (const float*)d_in[6];
  const float* c1_b  = (const float*)d_in[7];
  const float* c2_w  = (const float*)d_in[8];
  const float* c2_we = (const float*)d_in[9];
  const float* c2_as = (const float*)d_in[10];
  const float* c2_ad = (const float*)d_in[11];
  const float* c2_ae = (const float*)d_in[12];
  const float* c2_b  = (const float*)d_in[13];
  const float* s_w1  = (const float*)d_in[14];
  const float* s_b1  = (const float*)d_in[15];
  const float* s_w2  = (const float*)d_in[16];
  const float* s_b2  = (const float*)d_in[17];
  const float* n_w1  = (const float*)d_in[18];
  const float* n_b1  = (const float*)d_in[19];
  const float* n_w2  = (const float*)d_in[20];
  const float* n_b2  = (const float*)d_in[21];
  const float* e_w1  = (const float*)d_in[22];
  const float* e_b1  = (const float*)d_in[23];
  const float* e_w2  = (const float*)d_in[24];
  const float* e_b2  = (const float*)d_in[25];
  const int* x    = (const int*)d_in[26];
  const int* ei   = (const int*)d_in[27];
  const int* ea   = (const int*)d_in[28];
  const int* nedg = (const int*)d_in[29];
  float* out = (float*)d_out;

  prep_kernel<<<dim3(44), dim3(256), 0, stream>>>(
      edge_tab, c1_w, c1_we, c1_ae, c2_w, c2_we, c2_ae,
      s_w1, n_w1, n_w2, e_w1);

  graph_kernel<<<dim3(B_GR/2), dim3(256), 0, stream>>>(
      node_tab, c1_as, c1_ad, c1_b, c2_as, c2_ad, c2_b,
      s_b1, s_w2, s_b2, n_b1, n_b2, e_b1, e_w2, e_b2,
      x, ei, ea, nedg, out);
}

// Round 10
// 190.053 us; speedup vs baseline: 1.3248x; 1.3248x over previous
//
#include <hip/hip_runtime.h>
#include <hip/hip_bf16.h>

// ---------------------------------------------------------------------------
// GNN action-value net, MI355X. Round 10: revert to r8 structure (r9's
// 2-graph/block batching spilled ~230MB/dispatch of scratch to HBM: VGPR
// fragment state doubled past the allocator budget). r8 + packed bf16
// converts (v_cvt_pk_bf16_f32) in the fragment preloads (register-neutral).
//  * 1024 blocks x 256 thr, 1 graph/block, LDS 38.9KB -> 4 blocks/CU.
//  * 10 barriers; fused addnode/addedge MFMA stage; wave-local row reuse.
// Fragment maps (verified r5-r8): A[m][k]: m=lane&15, k=(lane>>4)*8+j;
// B[k][n]: n=lane&15, k=(lane>>4)*8+j; C/D: col=lane&15, row=(lane>>4)*4+reg.
// ---------------------------------------------------------------------------

#define NPG 64
#define EPG 1024
#define NEPG 256
#define B_GR 1024
#define E_TOT 1048576
#define EMB 64
#define HID 128
#define NOUT 101
#define OUT_PG 6721            // 1 + 64*101 + 256

typedef __attribute__((ext_vector_type(8))) short bf16x8;
typedef __attribute__((ext_vector_type(4))) float f32x4;
typedef unsigned short ushort_t;

__device__ ushort_t g_c1w[EMB*HID];      // frag-packed bf16 (K=64)
__device__ ushort_t g_c2w[HID*HID];      // frag-packed bf16
__device__ ushort_t g_nw1[HID*HID];
__device__ ushort_t g_ew1[HID*HID];
__device__ ushort_t g_nw2[HID*112];      // N padded 101 -> 112
__device__ float    g_sw1t[HID*HID];     // s_w1 transposed, f32
__device__ float    g_he1[4], g_he2[4];

__device__ __forceinline__ ushort_t f2bf(float f) {
  unsigned u = __float_as_uint(f);
  return (ushort_t)((u + 0x7fffu + ((u >> 16) & 1u)) >> 16);
}
__device__ __forceinline__ float bf2f(ushort_t h) {
  return __uint_as_float(((unsigned)h) << 16);
}
// packed f32x2 -> bf16x2 (RTNE), returns the 2 bf16 in one uint
__device__ __forceinline__ unsigned pk2(float a, float b) {
  __hip_bfloat162 h = __float22bfloat162_rn(make_float2(a, b));
  unsigned r; __builtin_memcpy(&r, &h, 4); return r;
}
// build bf16x8 from two float4 (elements in order v0.xyzw v1.xyzw)
__device__ __forceinline__ bf16x8 pk8(float4 v0, float4 v1) {
  union { bf16x8 v; unsigned u[4]; } o;
  o.u[0] = pk2(v0.x, v0.y); o.u[1] = pk2(v0.z, v0.w);
  o.u[2] = pk2(v1.x, v1.y); o.u[3] = pk2(v1.z, v1.w);
  return o.v;
}

// ---------------------------------------------------------------------------
// prep: 44 blocks. b0: logit-constant dots. b1-4: c1w. b5-12: c2w.
// b13-20: nw1. b21-28: ew1. b29-35: nw2. b36-43: sw1t.
__global__ void prep_kernel(
    const float* __restrict__ edge_tab,
    const float* __restrict__ c1_w,  const float* __restrict__ c1_we,
    const float* __restrict__ c1_ae,
    const float* __restrict__ c2_w,  const float* __restrict__ c2_we,
    const float* __restrict__ c2_ae,
    const float* __restrict__ s_w1,  const float* __restrict__ n_w1,
    const float* __restrict__ n_w2,  const float* __restrict__ e_w1)
{
  const int b = blockIdx.x, tid = threadIdx.x;
  if (b == 0) {
    __shared__ float v1[EMB], v2[EMB];
    if (tid < EMB) {
      float a = 0.f, d = 0.f;
      for (int j = 0; j < HID; ++j) {
        a = fmaf(c1_we[tid*HID + j], c1_ae[j], a);
        d = fmaf(c2_we[tid*HID + j], c2_ae[j], d);
      }
      v1[tid] = a; v2[tid] = d;
    }
    __syncthreads();
    if (tid < 4) {
      float a = 0.f, d = 0.f;
      for (int k = 0; k < EMB; ++k) {
        const float ev = edge_tab[tid*EMB + k];
        a = fmaf(ev, v1[k], a); d = fmaf(ev, v2[k], d);
      }
      g_he1[tid] = a; g_he2[tid] = d;
    }
    return;
  }
  if (b <= 4) {
    const int base = (b - 1) * 2048 + tid;
    #pragma unroll
    for (int it = 0; it < 8; ++it) {
      const int idx = base + it*256;
      const int j = idx & 7, l = (idx >> 3) & 63, r2 = idx >> 9;
      const int ks = r2 & 1, ct = r2 >> 1;
      const int row = ks*32 + (l >> 4)*8 + j;
      const int col = ct*16 + (l & 15);
      g_c1w[idx] = f2bf(c1_w[row*HID + col]);
    }
    return;
  }
  if (b <= 28) {
    const int grp = (b - 5) >> 3;
    const int chunk = (b - 5) & 7;
    const float* W = (grp == 0) ? c2_w : (grp == 1) ? n_w1 : e_w1;
    ushort_t* G = (grp == 0) ? g_c2w : (grp == 1) ? g_nw1 : g_ew1;
    const int base = chunk * 2048 + tid;
    #pragma unroll
    for (int it = 0; it < 8; ++it) {
      const int idx = base + it*256;
      const int j = idx & 7, l = (idx >> 3) & 63, r2 = idx >> 9;
      const int ks = r2 & 3, ct = r2 >> 2;
      const int row = ks*32 + (l >> 4)*8 + j;
      const int col = ct*16 + (l & 15);
      G[idx] = f2bf(W[row*HID + col]);
    }
    return;
  }
  if (b <= 35) {
    const int base = (b - 29) * 2048 + tid;
    #pragma unroll
    for (int it = 0; it < 8; ++it) {
      const int idx = base + it*256;
      const int j = idx & 7, l = (idx >> 3) & 63, r2 = idx >> 9;
      const int ks = r2 & 3, ct = r2 >> 2;
      const int row = ks*32 + (l >> 4)*8 + j;
      const int col = ct*16 + (l & 15);
      g_nw2[idx] = (col < NOUT) ? f2bf(n_w2[row*NOUT + col]) : (ushort_t)0;
    }
    return;
  }
  {
    const int base = (b - 36) * 2048 + tid;
    #pragma unroll
    for (int it = 0; it < 8; ++it) {
      const int idx = base + it*256;
      g_sw1t[idx] = s_w1[(idx & 127)*HID + (idx >> 7)];
    }
  }
}

// ---------------------------------------------------------------------------
// LDS map (bytes). Region R overlays Pf(64x64 f32) / Hr(64x136 ushort).
#define S_HC   0        // 128x72 ushort col-major; reused as a1b 64x136 rows
#define S_R    18432    // max(Pf 16384, Hr 17408)
#define S_PART 35840    // 256 f32 (stop partials)
#define S_NS   36864    // 64 f32
#define S_ND   37120    // 64 f32
#define S_GP   37376    // 128 f32 (pool)
#define S_EBW  37888    // 256 f32: e_b1[0..127] | e_w2[0..127]
#define S_HCC  38912    // 8 f32
#define S_TOT  38944

__global__ __launch_bounds__(256, 4) void graph_kernel(
    const float* __restrict__ node_tab,
    const float* __restrict__ c1_as, const float* __restrict__ c1_ad,
    const float* __restrict__ c1_b,
    const float* __restrict__ c2_as, const float* __restrict__ c2_ad,
    const float* __restrict__ c2_b,
    const float* __restrict__ s_b1,  const float* __restrict__ s_w2,
    const float* __restrict__ s_b2,
    const float* __restrict__ n_b1,  const float* __restrict__ n_b2,
    const float* __restrict__ e_b1,  const float* __restrict__ e_w2,
    const float* __restrict__ e_b2,
    const int* __restrict__ x,  const int* __restrict__ ei,
    const int* __restrict__ ea, const int* __restrict__ nedg,
    float* __restrict__ out)
{
  const int tid = threadIdx.x;
  const int gid = blockIdx.x;
  const int nb = gid * NPG;
  const int lane = tid & 63;
  const int wv = tid >> 6;
  const int qd = lane >> 4;        // quad
  const int cl = lane & 15;        // col/row-in-tile
  const int rb = wv * 16;          // wave's M-tile base row

  __shared__ __align__(16) char smem[S_TOT];
  ushort_t* Hc   = (ushort_t*)(smem + S_HC);   // stride 72 (feat-major)
  float*    Pf   = (float*)   (smem + S_R);    // 64x64 f32
  ushort_t* Hr   = (ushort_t*)(smem + S_R);    // stride 136 (row-major)
  float*    part = (float*)   (smem + S_PART);
  float*    ns   = (float*)   (smem + S_NS);
  float*    nd   = (float*)   (smem + S_ND);
  float*    gp   = (float*)   (smem + S_GP);
  float*    ebw  = (float*)   (smem + S_EBW);
  float*    hc   = (float*)   (smem + S_HCC);
  ushort_t* a1b  = Hc;                         // 64x136 rows

  // ---- P0: edge regs, pair regs, emb frags, zero Pf/gp, consts ----
  unsigned er[4];
  #pragma unroll
  for (int i = 0; i < 4; ++i) {
    const int k = tid + 256*i;
    const int s = ei[gid*EPG + k] - nb;
    const int d = ei[E_TOT + gid*EPG + k] - nb;
    const int t = ea[gid*EPG + k];
    er[i] = (unsigned)(s | (d << 6) | (t << 12));
  }
  const int2 prr = *(const int2*)(nedg + 2*(gid*NEPG + tid));
  bf16x8 ea0, ea1;                 // emb A-frags for row rb+cl
  {
    const int cat = x[nb + rb + cl];
    const float* src = node_tab + cat*EMB;
    ea0 = pk8(*(const float4*)(src + qd*8),      *(const float4*)(src + qd*8 + 4));
    ea1 = pk8(*(const float4*)(src + 32 + qd*8), *(const float4*)(src + 36 + qd*8));
  }
  {
    float4* pz = (float4*)Pf;
    #pragma unroll
    for (int j = 0; j < 4; ++j) pz[tid + j*256] = make_float4(0.f,0.f,0.f,0.f);
  }
  if (tid < 128) gp[tid] = 0.f;
  ebw[tid] = (tid < 128) ? e_b1[tid] : e_w2[tid - 128];
  if (tid < 8) hc[tid] = (tid < 4) ? g_he1[tid] : g_he2[tid-4];

  // ---- P2: h1pre = emb @ c1_w (MFMA) -> Hc col-major + ns/nd ----
  {
    float pns[4] = {0.f,0.f,0.f,0.f}, pnd[4] = {0.f,0.f,0.f,0.f};
    #pragma unroll
    for (int ct = 0; ct < 8; ++ct) {
      f32x4 acc = {0.f, 0.f, 0.f, 0.f};
      const bf16x8 b0 = *(const bf16x8*)(g_c1w + ((ct*2+0)*64 + lane)*8);
      const bf16x8 b1 = *(const bf16x8*)(g_c1w + ((ct*2+1)*64 + lane)*8);
      acc = __builtin_amdgcn_mfma_f32_16x16x32_bf16(ea0, b0, acc, 0, 0, 0);
      acc = __builtin_amdgcn_mfma_f32_16x16x32_bf16(ea1, b1, acc, 0, 0, 0);
      const int n = ct*16 + cl;
      const float asv = c1_as[n], adv = c1_ad[n];
      #pragma unroll
      for (int r = 0; r < 4; ++r) {
        const float v = acc[r];
        Hc[n*72 + (rb + qd*4 + r)] = f2bf(v);
        pns[r] = fmaf(v, asv, pns[r]);
        pnd[r] = fmaf(v, adv, pnd[r]);
      }
    }
    #pragma unroll
    for (int r = 0; r < 4; ++r) {
      #pragma unroll
      for (int off = 1; off < 16; off <<= 1) {
        pns[r] += __shfl_xor(pns[r], off, 64);
        pnd[r] += __shfl_xor(pnd[r], off, 64);
      }
    }
    if (cl == 0) {
      #pragma unroll
      for (int r = 0; r < 4; ++r) { ns[rb+qd*4+r] = pns[r]; nd[rb+qd*4+r] = pnd[r]; }
    }
  }
  __syncthreads();                                        // B2

  // ---- edge pass 1 ----
  #pragma unroll
  for (int i = 0; i < 4; ++i) {
    const unsigned tp = er[i];
    const int s = tp & 63, d = (tp >> 6) & 63, t = tp >> 12;
    float l = ns[s] + nd[d] + hc[t];
    l = (l > 0.f) ? l : 0.2f * l;
    atomicAdd(&Pf[d*64 + s], __expf(l));
  }
  __syncthreads();                                        // B3

  // ---- agg1 preload: P frags (f32->bf16 in-reg) + den rowsum ----
  bf16x8 pa0, pa1;
  float inv4[4];
  {
    const float* pr = Pf + (rb + cl)*64;
    const float4 v0 = *(const float4*)(pr + qd*8);
    const float4 v1 = *(const float4*)(pr + qd*8 + 4);
    const float4 v2 = *(const float4*)(pr + 32 + qd*8);
    const float4 v3 = *(const float4*)(pr + 36 + qd*8);
    pa0 = pk8(v0, v1); pa1 = pk8(v2, v3);
    float den = v0.x+v0.y+v0.z+v0.w + v1.x+v1.y+v1.z+v1.w
              + v2.x+v2.y+v2.z+v2.w + v3.x+v3.y+v3.z+v3.w;
    den += __shfl_xor(den, 16, 64);
    den += __shfl_xor(den, 32, 64);
    #pragma unroll
    for (int r = 0; r < 4; ++r)
      inv4[r] = 1.f / (__shfl(den, qd*4 + r, 64) + 1e-16f);
  }
  __syncthreads();                                        // B4

  // ---- agg1: h1 = relu(inv*(P@h1pre) + c1_b) -> Hr ----
  {
    #pragma unroll
    for (int ct = 0; ct < 8; ++ct) {
      f32x4 acc = {0.f, 0.f, 0.f, 0.f};
      const bf16x8 b0 = *(const bf16x8*)(Hc + (ct*16+cl)*72 + qd*8);
      const bf16x8 b1 = *(const bf16x8*)(Hc + (ct*16+cl)*72 + 32 + qd*8);
      acc = __builtin_amdgcn_mfma_f32_16x16x32_bf16(pa0, b0, acc, 0, 0, 0);
      acc = __builtin_amdgcn_mfma_f32_16x16x32_bf16(pa1, b1, acc, 0, 0, 0);
      const int n = ct*16 + cl;
      const float bias = c1_b[n];
      #pragma unroll
      for (int r = 0; r < 4; ++r)
        Hr[(rb + qd*4 + r)*136 + n] = f2bf(fmaxf(fmaf(acc[r], inv4[r], bias), 0.f));
    }
  }
  bf16x8 h1f[4];                     // wave-local rows, no barrier needed
  #pragma unroll
  for (int ks = 0; ks < 4; ++ks)
    h1f[ks] = *(const bf16x8*)(Hr + (rb+cl)*136 + ks*32 + qd*8);
  __syncthreads();                                        // B5

  // ---- P7: h2pre = h1 @ c2_w -> Hc + ns/nd; zero Pf ----
  {
    float4* pz = (float4*)Pf;
    #pragma unroll
    for (int j = 0; j < 4; ++j) pz[tid + j*256] = make_float4(0.f,0.f,0.f,0.f);
    float pns[4] = {0.f,0.f,0.f,0.f}, pnd[4] = {0.f,0.f,0.f,0.f};
    #pragma unroll
    for (int ct = 0; ct < 8; ++ct) {
      f32x4 acc = {0.f, 0.f, 0.f, 0.f};
      #pragma unroll
      for (int ks = 0; ks < 4; ++ks) {
        const bf16x8 b = *(const bf16x8*)(g_c2w + ((ct*4+ks)*64 + lane)*8);
        acc = __builtin_amdgcn_mfma_f32_16x16x32_bf16(h1f[ks], b, acc, 0, 0, 0);
      }
      const int n = ct*16 + cl;
      const float asv = c2_as[n], adv = c2_ad[n];
      #pragma unroll
      for (int r = 0; r < 4; ++r) {
        const float v = acc[r];
        Hc[n*72 + (rb + qd*4 + r)] = f2bf(v);
        pns[r] = fmaf(v, asv, pns[r]);
        pnd[r] = fmaf(v, adv, pnd[r]);
      }
    }
    #pragma unroll
    for (int r = 0; r < 4; ++r) {
      #pragma unroll
      for (int off = 1; off < 16; off <<= 1) {
        pns[r] += __shfl_xor(pns[r], off, 64);
        pnd[r] += __shfl_xor(pnd[r], off, 64);
      }
    }
    if (cl == 0) {
      #pragma unroll
      for (int r = 0; r < 4; ++r) { ns[rb+qd*4+r] = pns[r]; nd[rb+qd*4+r] = pnd[r]; }
    }
  }
  __syncthreads();                                        // B6

  // ---- edge pass 2 ----
  #pragma unroll
  for (int i = 0; i < 4; ++i) {
    const unsigned tp = er[i];
    const int s = tp & 63, d = (tp >> 6) & 63, t = tp >> 12;
    float l = ns[s] + nd[d] + hc[4 + t];
    l = (l > 0.f) ? l : 0.2f * l;
    atomicAdd(&Pf[d*64 + s], __expf(l));
  }
  __syncthreads();                                        // B7

  // ---- agg2 preload ----
  {
    const float* pr = Pf + (rb + cl)*64;
    const float4 v0 = *(const float4*)(pr + qd*8);
    const float4 v1 = *(const float4*)(pr + qd*8 + 4);
    const float4 v2 = *(const float4*)(pr + 32 + qd*8);
    const float4 v3 = *(const float4*)(pr + 36 + qd*8);
    pa0 = pk8(v0, v1); pa1 = pk8(v2, v3);
    float den = v0.x+v0.y+v0.z+v0.w + v1.x+v1.y+v1.z+v1.w
              + v2.x+v2.y+v2.z+v2.w + v3.x+v3.y+v3.z+v3.w;
    den += __shfl_xor(den, 16, 64);
    den += __shfl_xor(den, 32, 64);
    #pragma unroll
    for (int r = 0; r < 4; ++r)
      inv4[r] = 1.f / (__shfl(den, qd*4 + r, 64) + 1e-16f);
  }
  __syncthreads();                                        // B8

  // ---- agg2: h2 = inv*(P@h2pre) + c2_b -> Hr + pooling ----
  {
    #pragma unroll
    for (int ct = 0; ct < 8; ++ct) {
      f32x4 acc = {0.f, 0.f, 0.f, 0.f};
      const bf16x8 b0 = *(const bf16x8*)(Hc + (ct*16+cl)*72 + qd*8);
      const bf16x8 b1 = *(const bf16x8*)(Hc + (ct*16+cl)*72 + 32 + qd*8);
      acc = __builtin_amdgcn_mfma_f32_16x16x32_bf16(pa0, b0, acc, 0, 0, 0);
      acc = __builtin_amdgcn_mfma_f32_16x16x32_bf16(pa1, b1, acc, 0, 0, 0);
      const int n = ct*16 + cl;
      const float bias = c2_b[n];
      float colsum = 0.f;
      #pragma unroll
      for (int r = 0; r < 4; ++r) {
        const float v = fmaf(acc[r], inv4[r], bias);
        Hr[(rb + qd*4 + r)*136 + n] = f2bf(v);
        colsum += v;
      }
      colsum += __shfl_xor(colsum, 16, 64);
      colsum += __shfl_xor(colsum, 32, 64);
      if (qd == 0) atomicAdd(&gp[n], colsum);
    }
  }
  __syncthreads();                                        // B9

  // ---- stop head partials ----
  {
    const int j = tid & 127, half = tid >> 7;
    const float* wr = g_sw1t + j*HID + half*64;
    const float* gr = gp + half*64;
    float p = 0.f;
    #pragma unroll
    for (int q = 0; q < 16; ++q) {
      const float4 w = ((const float4*)wr)[q];
      const float4 g = ((const float4*)gr)[q];
      p = fmaf(w.x, g.x, p); p = fmaf(w.y, g.y, p);
      p = fmaf(w.z, g.z, p); p = fmaf(w.w, g.w, p);
    }
    part[tid] = p;
  }
  __syncthreads();                                        // B10

  // ---- post-B10: stop reduce (wave 0), fused addnode/addedge staging ----
  if (tid < 64) {
    const float z0 = fmaxf(part[tid] + part[tid+128] + s_b1[tid], 0.f);
    const float z1 = fmaxf(part[tid+64] + part[tid+192] + s_b1[tid+64], 0.f);
    float p = fmaf(z0, s_w2[tid], z1 * s_w2[tid+64]);
    #pragma unroll
    for (int off = 32; off > 0; off >>= 1) p += __shfl_down(p, off, 64);
    if (tid == 0) out[(size_t)gid*OUT_PG] = p + s_b2[0];
  }

  bf16x8 h2f[4];                    // own-wave h2 rows (agg2 wrote them)
  #pragma unroll
  for (int ks = 0; ks < 4; ++ks)
    h2f[ks] = *(const bf16x8*)(Hr + (rb+cl)*136 + ks*32 + qd*8);

  // fused: a1 = relu(h2@n_w1+n_b1) -> a1b(Hc);  u = h2@e_w1 -> Hr (own rows)
  {
    #pragma unroll
    for (int ct = 0; ct < 8; ++ct) {
      f32x4 an = {0.f, 0.f, 0.f, 0.f};
      f32x4 ae2 = {0.f, 0.f, 0.f, 0.f};
      #pragma unroll
      for (int ks = 0; ks < 4; ++ks) {
        const bf16x8 bn = *(const bf16x8*)(g_nw1 + ((ct*4+ks)*64 + lane)*8);
        const bf16x8 be = *(const bf16x8*)(g_ew1 + ((ct*4+ks)*64 + lane)*8);
        an  = __builtin_amdgcn_mfma_f32_16x16x32_bf16(h2f[ks], bn, an, 0, 0, 0);
        ae2 = __builtin_amdgcn_mfma_f32_16x16x32_bf16(h2f[ks], be, ae2, 0, 0, 0);
      }
      const int n = ct*16 + cl;
      const float bias = n_b1[n];
      #pragma unroll
      for (int r = 0; r < 4; ++r) {
        a1b[(rb + qd*4 + r)*136 + n] = f2bf(fmaxf(an[r] + bias, 0.f));
        Hr[(rb + qd*4 + r)*136 + n] = f2bf(ae2[r]);
      }
    }
  }
  // addnode head: out = a1 @ n_w2p + n_b2 (own-wave a1b rows)
  {
    bf16x8 af[4];
    #pragma unroll
    for (int ks = 0; ks < 4; ++ks)
      af[ks] = *(const bf16x8*)(a1b + (rb+cl)*136 + ks*32 + qd*8);
    float* ob = out + (size_t)gid*OUT_PG + 1;
    #pragma unroll
    for (int ct = 0; ct < 7; ++ct) {
      f32x4 acc = {0.f, 0.f, 0.f, 0.f};
      #pragma unroll
      for (int ks = 0; ks < 4; ++ks) {
        const bf16x8 b = *(const bf16x8*)(g_nw2 + ((ct*4+ks)*64 + lane)*8);
        acc = __builtin_amdgcn_mfma_f32_16x16x32_bf16(af[ks], b, acc, 0, 0, 0);
      }
      const int o = ct*16 + cl;
      if (o < NOUT) {
        const float b2 = n_b2[o];
        #pragma unroll
        for (int r = 0; r < 4; ++r)
          ob[(size_t)(rb + qd*4 + r)*NOUT + o] = acc[r] + b2;
      }
    }
  }
  __syncthreads();                                        // B12

  // ---- addedge pairs (u in Hr region) ----
  {
    const ushort_t* ui = Hr + (prr.x - nb)*136;
    const ushort_t* uj = Hr + (prr.y - nb)*136;
    float ssum = 0.f;
    #pragma unroll
    for (int q8 = 0; q8 < 16; ++q8) {
      const bf16x8 va = *(const bf16x8*)(ui + q8*8);
      const bf16x8 vb = *(const bf16x8*)(uj + q8*8);
      #pragma unroll
      for (int j = 0; j < 8; ++j) {
        const int c = q8*8 + j;
        float v = bf2f((ushort_t)va[j]) + bf2f((ushort_t)vb[j]) + ebw[c];
        v = fmaxf(v, 0.f);
        ssum = fmaf(v, ebw[128 + c], ssum);
      }
    }
    out[(size_t)gid*OUT_PG + 1 + NPG*NOUT + tid] = ssum + e_b2[0];
  }
}

// ---------------------------------------------------------------------------
extern "C" void kernel_launch(void* const* d_in, const int* in_sizes, int n_in,
                              void* d_out, int out_size, void* d_ws, size_t ws_size,
                              hipStream_t stream) {
  const float* node_tab = (const float*)d_in[0];
  const float* edge_tab = (const float*)d_in[1];
  const float* c1_w  = (const float*)d_in[2];
  const float* c1_we = (const float*)d_in[3];
  const float* c1_as = (const float*)d_in[4];
  const float* c1_ad = (const float*)d_in[5];
  const float* c1_ae = (const float*)d_in[6];
  const float* c1_b  = (const float*)d_in[7];
  const float* c2_w  = (const float*)d_in[8];
  const float* c2_we = (const float*)d_in[9];
  const float* c2_as = (const float*)d_in[10];
  const float* c2_ad = (const float*)d_in[11];
  const float* c2_ae = (const float*)d_in[12];
  const float* c2_b  = (const float*)d_in[13];
  const float* s_w1  = (const float*)d_in[14];
  const float* s_b1  = (const float*)d_in[15];
  const float* s_w2  = (const float*)d_in[16];
  const float* s_b2  = (const float*)d_in[17];
  const float* n_w1  = (const float*)d_in[18];
  const float* n_b1  = (const float*)d_in[19];
  const float* n_w2  = (const float*)d_in[20];
  const float* n_b2  = (const float*)d_in[21];
  const float* e_w1  = (const float*)d_in[22];
  const float* e_b1  = (const float*)d_in[23];
  const float* e_w2  = (const float*)d_in[24];
  const float* e_b2  = (const float*)d_in[25];
  const int* x    = (const int*)d_in[26];
  const int* ei   = (const int*)d_in[27];
  const int* ea   = (const int*)d_in[28];
  const int* nedg = (const int*)d_in[29];
  float* out = (float*)d_out;

  prep_kernel<<<dim3(44), dim3(256), 0, stream>>>(
      edge_tab, c1_w, c1_we, c1_ae, c2_w, c2_we, c2_ae,
      s_w1, n_w1, n_w2, e_w1);

  graph_kernel<<<dim3(B_GR), dim3(256), 0, stream>>>(
      node_tab, c1_as, c1_ad, c1_b, c2_as, c2_ad, c2_b,
      s_b1, s_w2, s_b2, n_b1, n_b2, e_b1, e_w2, e_b2,
      x, ei, ea, nedg, out);
}

// Round 11
// 187.747 us; speedup vs baseline: 1.3411x; 1.0123x over previous
//
#include <hip/hip_runtime.h>
#include <hip/hip_bf16.h>

// ---------------------------------------------------------------------------
// GNN action-value net, MI355X. Round 11: layer-1 fully table-ized.
//  * nt1 = node_tab@c1_w (100x128 bf16) + per-category attn scalars hs1/hd1
//    precomputed in prep -> P2 (in-block emb matmul + epilogue) deleted.
//  * Layer-1 edge pass and the nt1->Hc gather share one phase (independent:
//    expf+LDS atomics overlap the gather's global loads).
//  * Otherwise r10 structure: 1024 blocks, LDS 39.2KB -> 4 blocks/CU,
//    10 barriers, fused addnode/addedge MFMA stage, wave-local row reuse.
// Fragment maps (verified r5-r10): A[m][k]: m=lane&15, k=(lane>>4)*8+j;
// B[k][n]: n=lane&15, k=(lane>>4)*8+j; C/D: col=lane&15, row=(lane>>4)*4+reg.
// ---------------------------------------------------------------------------

#define NPG 64
#define EPG 1024
#define NEPG 256
#define B_GR 1024
#define E_TOT 1048576
#define EMB 64
#define HID 128
#define NOUT 101
#define OUT_PG 6721            // 1 + 64*101 + 256

typedef __attribute__((ext_vector_type(8))) short bf16x8;
typedef __attribute__((ext_vector_type(4))) float f32x4;
typedef unsigned short ushort_t;

__device__ ushort_t g_nt1[100*HID];      // bf16 rows: node_tab @ c1_w
__device__ ushort_t g_c2w[HID*HID];      // frag-packed bf16
__device__ ushort_t g_nw1[HID*HID];
__device__ ushort_t g_ew1[HID*HID];
__device__ ushort_t g_nw2[HID*112];      // N padded 101 -> 112
__device__ float    g_sw1t[HID*HID];     // s_w1 transposed, f32
__device__ float    g_hs1[128], g_hd1[128];   // per-category attn scalars
__device__ float    g_he1[4], g_he2[4];

__device__ __forceinline__ ushort_t f2bf(float f) {
  unsigned u = __float_as_uint(f);
  return (ushort_t)((u + 0x7fffu + ((u >> 16) & 1u)) >> 16);
}
__device__ __forceinline__ float bf2f(ushort_t h) {
  return __uint_as_float(((unsigned)h) << 16);
}
__device__ __forceinline__ unsigned pk2(float a, float b) {
  __hip_bfloat162 h = __float22bfloat162_rn(make_float2(a, b));
  unsigned r; __builtin_memcpy(&r, &h, 4); return r;
}
__device__ __forceinline__ bf16x8 pk8(float4 v0, float4 v1) {
  union { bf16x8 v; unsigned u[4]; } o;
  o.u[0] = pk2(v0.x, v0.y); o.u[1] = pk2(v0.z, v0.w);
  o.u[2] = pk2(v1.x, v1.y); o.u[3] = pk2(v1.z, v1.w);
  return o.v;
}

// ---------------------------------------------------------------------------
// prep: 91 blocks. b0: logit consts. b1-50: nt1. b51: hs1/hd1.
// b52-75: c2w/nw1/ew1. b76-82: nw2. b83-90: sw1t.
__global__ void prep_kernel(
    const float* __restrict__ node_tab, const float* __restrict__ edge_tab,
    const float* __restrict__ c1_w,  const float* __restrict__ c1_we,
    const float* __restrict__ c1_as, const float* __restrict__ c1_ad,
    const float* __restrict__ c1_ae,
    const float* __restrict__ c2_w,  const float* __restrict__ c2_we,
    const float* __restrict__ c2_ae,
    const float* __restrict__ s_w1,  const float* __restrict__ n_w1,
    const float* __restrict__ n_w2,  const float* __restrict__ e_w1)
{
  const int b = blockIdx.x, tid = threadIdx.x;
  if (b == 0) {                       // per-edge-type logit constants
    __shared__ float v1[EMB], v2[EMB];
    if (tid < EMB) {
      float a = 0.f, d = 0.f;
      for (int j = 0; j < HID; ++j) {
        a = fmaf(c1_we[tid*HID + j], c1_ae[j], a);
        d = fmaf(c2_we[tid*HID + j], c2_ae[j], d);
      }
      v1[tid] = a; v2[tid] = d;
    }
    __syncthreads();
    if (tid < 4) {
      float a = 0.f, d = 0.f;
      for (int k = 0; k < EMB; ++k) {
        const float ev = edge_tab[tid*EMB + k];
        a = fmaf(ev, v1[k], a); d = fmaf(ev, v2[k], d);
      }
      g_he1[tid] = a; g_he2[tid] = d;
    }
    return;
  }
  if (b <= 50) {                      // nt1 = node_tab @ c1_w (100x128)
    const int idx = (b - 1) * 256 + tid;
    const int i = idx >> 7, j = idx & (HID - 1);
    float s = 0.f;
    #pragma unroll 8
    for (int k = 0; k < EMB; ++k) s = fmaf(node_tab[i*EMB + k], c1_w[k*HID + j], s);
    g_nt1[idx] = f2bf(s);
    return;
  }
  if (b == 51) {                      // per-category attention scalars
    __shared__ float vs[EMB], vd[EMB];
    if (tid < EMB) {
      float a = 0.f, d = 0.f;
      for (int j = 0; j < HID; ++j) {
        const float w = c1_w[tid*HID + j];
        a = fmaf(w, c1_as[j], a); d = fmaf(w, c1_ad[j], d);
      }
      vs[tid] = a; vd[tid] = d;
    }
    __syncthreads();
    if (tid < 128) {
      float a = 0.f, d = 0.f;
      if (tid < 100) {
        for (int k = 0; k < EMB; ++k) {
          const float xv = node_tab[tid*EMB + k];
          a = fmaf(xv, vs[k], a); d = fmaf(xv, vd[k], d);
        }
      }
      g_hs1[tid] = a; g_hd1[tid] = d;
    }
    return;
  }
  if (b <= 75) {                      // c2w / nw1 / ew1: 16384 each, 8 chunks
    const int grp = (b - 52) >> 3;
    const int chunk = (b - 52) & 7;
    const float* W = (grp == 0) ? c2_w : (grp == 1) ? n_w1 : e_w1;
    ushort_t* G = (grp == 0) ? g_c2w : (grp == 1) ? g_nw1 : g_ew1;
    const int base = chunk * 2048 + tid;
    #pragma unroll
    for (int it = 0; it < 8; ++it) {
      const int idx = base + it*256;
      const int j = idx & 7, l = (idx >> 3) & 63, r2 = idx >> 9;
      const int ks = r2 & 3, ct = r2 >> 2;
      const int row = ks*32 + (l >> 4)*8 + j;
      const int col = ct*16 + (l & 15);
      G[idx] = f2bf(W[row*HID + col]);
    }
    return;
  }
  if (b <= 82) {                      // nw2: 14336, 7 chunks
    const int base = (b - 76) * 2048 + tid;
    #pragma unroll
    for (int it = 0; it < 8; ++it) {
      const int idx = base + it*256;
      const int j = idx & 7, l = (idx >> 3) & 63, r2 = idx >> 9;
      const int ks = r2 & 3, ct = r2 >> 2;
      const int row = ks*32 + (l >> 4)*8 + j;
      const int col = ct*16 + (l & 15);
      g_nw2[idx] = (col < NOUT) ? f2bf(n_w2[row*NOUT + col]) : (ushort_t)0;
    }
    return;
  }
  {                                   // sw1t: 16384, 8 chunks
    const int base = (b - 83) * 2048 + tid;
    #pragma unroll
    for (int it = 0; it < 8; ++it) {
      const int idx = base + it*256;
      g_sw1t[idx] = s_w1[(idx & 127)*HID + (idx >> 7)];
    }
  }
}

// ---------------------------------------------------------------------------
// LDS map (bytes). Region R overlays Pf(64x64 f32) / Hr(64x136 ushort).
#define S_HC   0        // 128x72 ushort feat-major; reused as a1b 64x136 rows
#define S_R    18432    // max(Pf 16384, Hr 17408)
#define S_PART 35840    // 256 f32 (stop partials)
#define S_NS   36864    // 64 f32
#define S_ND   37120    // 64 f32
#define S_GP   37376    // 128 f32 (pool)
#define S_EBW  37888    // 256 f32: e_b1[0..127] | e_w2[0..127]
#define S_HCC  38912    // 8 f32
#define S_XS   38944    // 64 int
#define S_TOT  39200

__global__ __launch_bounds__(256, 4) void graph_kernel(
    const float* __restrict__ c1_b,
    const float* __restrict__ c2_as, const float* __restrict__ c2_ad,
    const float* __restrict__ c2_b,
    const float* __restrict__ s_b1,  const float* __restrict__ s_w2,
    const float* __restrict__ s_b2,
    const float* __restrict__ n_b1,  const float* __restrict__ n_b2,
    const float* __restrict__ e_b1,  const float* __restrict__ e_w2,
    const float* __restrict__ e_b2,
    const int* __restrict__ x,  const int* __restrict__ ei,
    const int* __restrict__ ea, const int* __restrict__ nedg,
    float* __restrict__ out)
{
  const int tid = threadIdx.x;
  const int gid = blockIdx.x;
  const int nb = gid * NPG;
  const int lane = tid & 63;
  const int wv = tid >> 6;
  const int qd = lane >> 4;        // quad
  const int cl = lane & 15;        // col/row-in-tile
  const int rb = wv * 16;          // wave's M-tile base row

  __shared__ __align__(16) char smem[S_TOT];
  ushort_t* Hc   = (ushort_t*)(smem + S_HC);   // [feat*72 + node]
  float*    Pf   = (float*)   (smem + S_R);    // 64x64 f32
  ushort_t* Hr   = (ushort_t*)(smem + S_R);    // stride 136 (row-major)
  float*    part = (float*)   (smem + S_PART);
  float*    ns   = (float*)   (smem + S_NS);
  float*    nd   = (float*)   (smem + S_ND);
  float*    gp   = (float*)   (smem + S_GP);
  float*    ebw  = (float*)   (smem + S_EBW);
  float*    hc   = (float*)   (smem + S_HCC);
  int*      xs   = (int*)     (smem + S_XS);
  ushort_t* a1b  = Hc;                         // 64x136 rows

  // ---- P0: edge regs, pair regs, xs -> ns/nd tables, zero Pf/gp, consts ----
  unsigned er[4];
  #pragma unroll
  for (int i = 0; i < 4; ++i) {
    const int k = tid + 256*i;
    const int s = ei[gid*EPG + k] - nb;
    const int d = ei[E_TOT + gid*EPG + k] - nb;
    const int t = ea[gid*EPG + k];
    er[i] = (unsigned)(s | (d << 6) | (t << 12));
  }
  const int2 prr = *(const int2*)(nedg + 2*(gid*NEPG + tid));
  if (tid < NPG) {
    const int cat = x[nb + tid];
    xs[tid] = cat;
    ns[tid] = g_hs1[cat];
    nd[tid] = g_hd1[cat];
  }
  {
    float4* pz = (float4*)Pf;
    #pragma unroll
    for (int j = 0; j < 4; ++j) pz[tid + j*256] = make_float4(0.f,0.f,0.f,0.f);
  }
  if (tid < 128) gp[tid] = 0.f;
  ebw[tid] = (tid < 128) ? e_b1[tid] : e_w2[tid - 128];
  if (tid < 8) hc[tid] = (tid < 4) ? g_he1[tid] : g_he2[tid-4];
  __syncthreads();                                        // B1

  // ---- E1+G: layer-1 edge pass (atomics) overlapped with nt1->Hc gather ----
  {
    const int gn = tid >> 2;
    const int f0 = (tid & 3) * 32;
    const ushort_t* srcp = g_nt1 + xs[gn]*HID + f0;
    const bf16x8 t0 = ((const bf16x8*)srcp)[0];
    const bf16x8 t1 = ((const bf16x8*)srcp)[1];
    const bf16x8 t2 = ((const bf16x8*)srcp)[2];
    const bf16x8 t3 = ((const bf16x8*)srcp)[3];
    #pragma unroll
    for (int i = 0; i < 4; ++i) {
      const unsigned tp = er[i];
      const int s = tp & 63, d = (tp >> 6) & 63, t = tp >> 12;
      float l = ns[s] + nd[d] + hc[t];
      l = (l > 0.f) ? l : 0.2f * l;
      atomicAdd(&Pf[d*64 + s], __expf(l));
    }
    #pragma unroll
    for (int q = 0; q < 8; ++q) {
      Hc[(f0 +      q)*72 + gn] = (ushort_t)t0[q];
      Hc[(f0 +  8 + q)*72 + gn] = (ushort_t)t1[q];
      Hc[(f0 + 16 + q)*72 + gn] = (ushort_t)t2[q];
      Hc[(f0 + 24 + q)*72 + gn] = (ushort_t)t3[q];
    }
  }
  __syncthreads();                                        // B2

  // ---- agg1 preload: P frags (f32->bf16 in-reg) + den rowsum ----
  bf16x8 pa0, pa1;
  float inv4[4];
  {
    const float* pr = Pf + (rb + cl)*64;
    const float4 v0 = *(const float4*)(pr + qd*8);
    const float4 v1 = *(const float4*)(pr + qd*8 + 4);
    const float4 v2 = *(const float4*)(pr + 32 + qd*8);
    const float4 v3 = *(const float4*)(pr + 36 + qd*8);
    pa0 = pk8(v0, v1); pa1 = pk8(v2, v3);
    float den = v0.x+v0.y+v0.z+v0.w + v1.x+v1.y+v1.z+v1.w
              + v2.x+v2.y+v2.z+v2.w + v3.x+v3.y+v3.z+v3.w;
    den += __shfl_xor(den, 16, 64);
    den += __shfl_xor(den, 32, 64);
    #pragma unroll
    for (int r = 0; r < 4; ++r)
      inv4[r] = 1.f / (__shfl(den, qd*4 + r, 64) + 1e-16f);
  }
  __syncthreads();                                        // B3

  // ---- agg1: h1 = relu(inv*(P@h1pre) + c1_b) -> Hr ----
  {
    #pragma unroll
    for (int ct = 0; ct < 8; ++ct) {
      f32x4 acc = {0.f, 0.f, 0.f, 0.f};
      const bf16x8 b0 = *(const bf16x8*)(Hc + (ct*16+cl)*72 + qd*8);
      const bf16x8 b1 = *(const bf16x8*)(Hc + (ct*16+cl)*72 + 32 + qd*8);
      acc = __builtin_amdgcn_mfma_f32_16x16x32_bf16(pa0, b0, acc, 0, 0, 0);
      acc = __builtin_amdgcn_mfma_f32_16x16x32_bf16(pa1, b1, acc, 0, 0, 0);
      const int n = ct*16 + cl;
      const float bias = c1_b[n];
      #pragma unroll
      for (int r = 0; r < 4; ++r)
        Hr[(rb + qd*4 + r)*136 + n] = f2bf(fmaxf(fmaf(acc[r], inv4[r], bias), 0.f));
    }
  }
  bf16x8 h1f[4];                     // wave-local rows, no barrier needed
  #pragma unroll
  for (int ks = 0; ks < 4; ++ks)
    h1f[ks] = *(const bf16x8*)(Hr + (rb+cl)*136 + ks*32 + qd*8);
  __syncthreads();                                        // B4

  // ---- P7: h2pre = h1 @ c2_w -> Hc + ns/nd; zero Pf ----
  {
    float4* pz = (float4*)Pf;
    #pragma unroll
    for (int j = 0; j < 4; ++j) pz[tid + j*256] = make_float4(0.f,0.f,0.f,0.f);
    float pns[4] = {0.f,0.f,0.f,0.f}, pnd[4] = {0.f,0.f,0.f,0.f};
    #pragma unroll
    for (int ct = 0; ct < 8; ++ct) {
      f32x4 acc = {0.f, 0.f, 0.f, 0.f};
      #pragma unroll
      for (int ks = 0; ks < 4; ++ks) {
        const bf16x8 b = *(const bf16x8*)(g_c2w + ((ct*4+ks)*64 + lane)*8);
        acc = __builtin_amdgcn_mfma_f32_16x16x32_bf16(h1f[ks], b, acc, 0, 0, 0);
      }
      const int n = ct*16 + cl;
      const float asv = c2_as[n], adv = c2_ad[n];
      #pragma unroll
      for (int r = 0; r < 4; ++r) {
        const float v = acc[r];
        Hc[n*72 + (rb + qd*4 + r)] = f2bf(v);
        pns[r] = fmaf(v, asv, pns[r]);
        pnd[r] = fmaf(v, adv, pnd[r]);
      }
    }
    #pragma unroll
    for (int r = 0; r < 4; ++r) {
      #pragma unroll
      for (int off = 1; off < 16; off <<= 1) {
        pns[r] += __shfl_xor(pns[r], off, 64);
        pnd[r] += __shfl_xor(pnd[r], off, 64);
      }
    }
    if (cl == 0) {
      #pragma unroll
      for (int r = 0; r < 4; ++r) { ns[rb+qd*4+r] = pns[r]; nd[rb+qd*4+r] = pnd[r]; }
    }
  }
  __syncthreads();                                        // B5

  // ---- edge pass 2 ----
  #pragma unroll
  for (int i = 0; i < 4; ++i) {
    const unsigned tp = er[i];
    const int s = tp & 63, d = (tp >> 6) & 63, t = tp >> 12;
    float l = ns[s] + nd[d] + hc[4 + t];
    l = (l > 0.f) ? l : 0.2f * l;
    atomicAdd(&Pf[d*64 + s], __expf(l));
  }
  __syncthreads();                                        // B6

  // ---- agg2 preload ----
  {
    const float* pr = Pf + (rb + cl)*64;
    const float4 v0 = *(const float4*)(pr + qd*8);
    const float4 v1 = *(const float4*)(pr + qd*8 + 4);
    const float4 v2 = *(const float4*)(pr + 32 + qd*8);
    const float4 v3 = *(const float4*)(pr + 36 + qd*8);
    pa0 = pk8(v0, v1); pa1 = pk8(v2, v3);
    float den = v0.x+v0.y+v0.z+v0.w + v1.x+v1.y+v1.z+v1.w
              + v2.x+v2.y+v2.z+v2.w + v3.x+v3.y+v3.z+v3.w;
    den += __shfl_xor(den, 16, 64);
    den += __shfl_xor(den, 32, 64);
    #pragma unroll
    for (int r = 0; r < 4; ++r)
      inv4[r] = 1.f / (__shfl(den, qd*4 + r, 64) + 1e-16f);
  }
  __syncthreads();                                        // B7

  // ---- agg2: h2 = inv*(P@h2pre) + c2_b -> Hr + pooling ----
  {
    #pragma unroll
    for (int ct = 0; ct < 8; ++ct) {
      f32x4 acc = {0.f, 0.f, 0.f, 0.f};
      const bf16x8 b0 = *(const bf16x8*)(Hc + (ct*16+cl)*72 + qd*8);
      const bf16x8 b1 = *(const bf16x8*)(Hc + (ct*16+cl)*72 + 32 + qd*8);
      acc = __builtin_amdgcn_mfma_f32_16x16x32_bf16(pa0, b0, acc, 0, 0, 0);
      acc = __builtin_amdgcn_mfma_f32_16x16x32_bf16(pa1, b1, acc, 0, 0, 0);
      const int n = ct*16 + cl;
      const float bias = c2_b[n];
      float colsum = 0.f;
      #pragma unroll
      for (int r = 0; r < 4; ++r) {
        const float v = fmaf(acc[r], inv4[r], bias);
        Hr[(rb + qd*4 + r)*136 + n] = f2bf(v);
        colsum += v;
      }
      colsum += __shfl_xor(colsum, 16, 64);
      colsum += __shfl_xor(colsum, 32, 64);
      if (qd == 0) atomicAdd(&gp[n], colsum);
    }
  }
  __syncthreads();                                        // B8

  // ---- stop head partials ----
  {
    const int j = tid & 127, half = tid >> 7;
    const float* wr = g_sw1t + j*HID + half*64;
    const float* gr = gp + half*64;
    float p = 0.f;
    #pragma unroll
    for (int q = 0; q < 16; ++q) {
      const float4 w = ((const float4*)wr)[q];
      const float4 g = ((const float4*)gr)[q];
      p = fmaf(w.x, g.x, p); p = fmaf(w.y, g.y, p);
      p = fmaf(w.z, g.z, p); p = fmaf(w.w, g.w, p);
    }
    part[tid] = p;
  }
  __syncthreads();                                        // B9

  // ---- post-B9: stop reduce (wave 0), fused addnode/addedge staging ----
  if (tid < 64) {
    const float z0 = fmaxf(part[tid] + part[tid+128] + s_b1[tid], 0.f);
    const float z1 = fmaxf(part[tid+64] + part[tid+192] + s_b1[tid+64], 0.f);
    float p = fmaf(z0, s_w2[tid], z1 * s_w2[tid+64]);
    #pragma unroll
    for (int off = 32; off > 0; off >>= 1) p += __shfl_down(p, off, 64);
    if (tid == 0) out[(size_t)gid*OUT_PG] = p + s_b2[0];
  }

  bf16x8 h2f[4];                    // own-wave h2 rows (agg2 wrote them)
  #pragma unroll
  for (int ks = 0; ks < 4; ++ks)
    h2f[ks] = *(const bf16x8*)(Hr + (rb+cl)*136 + ks*32 + qd*8);

  // fused: a1 = relu(h2@n_w1+n_b1) -> a1b(Hc);  u = h2@e_w1 -> Hr (own rows)
  {
    #pragma unroll
    for (int ct = 0; ct < 8; ++ct) {
      f32x4 an = {0.f, 0.f, 0.f, 0.f};
      f32x4 ae2 = {0.f, 0.f, 0.f, 0.f};
      #pragma unroll
      for (int ks = 0; ks < 4; ++ks) {
        const bf16x8 bn = *(const bf16x8*)(g_nw1 + ((ct*4+ks)*64 + lane)*8);
        const bf16x8 be = *(const bf16x8*)(g_ew1 + ((ct*4+ks)*64 + lane)*8);
        an  = __builtin_amdgcn_mfma_f32_16x16x32_bf16(h2f[ks], bn, an, 0, 0, 0);
        ae2 = __builtin_amdgcn_mfma_f32_16x16x32_bf16(h2f[ks], be, ae2, 0, 0, 0);
      }
      const int n = ct*16 + cl;
      const float bias = n_b1[n];
      #pragma unroll
      for (int r = 0; r < 4; ++r) {
        a1b[(rb + qd*4 + r)*136 + n] = f2bf(fmaxf(an[r] + bias, 0.f));
        Hr[(rb + qd*4 + r)*136 + n] = f2bf(ae2[r]);
      }
    }
  }
  // addnode head: out = a1 @ n_w2p + n_b2 (own-wave a1b rows)
  {
    bf16x8 af[4];
    #pragma unroll
    for (int ks = 0; ks < 4; ++ks)
      af[ks] = *(const bf16x8*)(a1b + (rb+cl)*136 + ks*32 + qd*8);
    float* ob = out + (size_t)gid*OUT_PG + 1;
    #pragma unroll
    for (int ct = 0; ct < 7; ++ct) {
      f32x4 acc = {0.f, 0.f, 0.f, 0.f};
      #pragma unroll
      for (int ks = 0; ks < 4; ++ks) {
        const bf16x8 b = *(const bf16x8*)(g_nw2 + ((ct*4+ks)*64 + lane)*8);
        acc = __builtin_amdgcn_mfma_f32_16x16x32_bf16(af[ks], b, acc, 0, 0, 0);
      }
      const int o = ct*16 + cl;
      if (o < NOUT) {
        const float b2 = n_b2[o];
        #pragma unroll
        for (int r = 0; r < 4; ++r)
          ob[(size_t)(rb + qd*4 + r)*NOUT + o] = acc[r] + b2;
      }
    }
  }
  __syncthreads();                                        // B10

  // ---- addedge pairs (u in Hr region) ----
  {
    const ushort_t* ui = Hr + (prr.x - nb)*136;
    const ushort_t* uj = Hr + (prr.y - nb)*136;
    float ssum = 0.f;
    #pragma unroll
    for (int q8 = 0; q8 < 16; ++q8) {
      const bf16x8 va = *(const bf16x8*)(ui + q8*8);
      const bf16x8 vb = *(const bf16x8*)(uj + q8*8);
      #pragma unroll
      for (int j = 0; j < 8; ++j) {
        const int c = q8*8 + j;
        float v = bf2f((ushort_t)va[j]) + bf2f((ushort_t)vb[j]) + ebw[c];
        v = fmaxf(v, 0.f);
        ssum = fmaf(v, ebw[128 + c], ssum);
      }
    }
    out[(size_t)gid*OUT_PG + 1 + NPG*NOUT + tid] = ssum + e_b2[0];
  }
}

// ---------------------------------------------------------------------------
extern "C" void kernel_launch(void* const* d_in, const int* in_sizes, int n_in,
                              void* d_out, int out_size, void* d_ws, size_t ws_size,
                              hipStream_t stream) {
  const float* node_tab = (const float*)d_in[0];
  const float* edge_tab = (const float*)d_in[1];
  const float* c1_w  = (const float*)d_in[2];
  const float* c1_we = (const float*)d_in[3];
  const float* c1_as = (const float*)d_in[4];
  const float* c1_ad = (const float*)d_in[5];
  const float* c1_ae = (const float*)d_in[6];
  const float* c1_b  = (const float*)d_in[7];
  const float* c2_w  = (const float*)d_in[8];
  const float* c2_we = (const float*)d_in[9];
  const float* c2_as = (const float*)d_in[10];
  const float* c2_ad = (const float*)d_in[11];
  const float* c2_ae = (const float*)d_in[12];
  const float* c2_b  = (const float*)d_in[13];
  const float* s_w1  = (const float*)d_in[14];
  const float* s_b1  = (const float*)d_in[15];
  const float* s_w2  = (const float*)d_in[16];
  const float* s_b2  = (const float*)d_in[17];
  const float* n_w1  = (const float*)d_in[18];
  const float* n_b1  = (const float*)d_in[19];
  const float* n_w2  = (const float*)d_in[20];
  const float* n_b2  = (const float*)d_in[21];
  const float* e_w1  = (const float*)d_in[22];
  const float* e_b1  = (const float*)d_in[23];
  const float* e_w2  = (const float*)d_in[24];
  const float* e_b2  = (const float*)d_in[25];
  const int* x    = (const int*)d_in[26];
  const int* ei   = (const int*)d_in[27];
  const int* ea   = (const int*)d_in[28];
  const int* nedg = (const int*)d_in[29];
  float* out = (float*)d_out;

  prep_kernel<<<dim3(91), dim3(256), 0, stream>>>(
      node_tab, edge_tab, c1_w, c1_we, c1_as, c1_ad, c1_ae,
      c2_w, c2_we, c2_ae, s_w1, n_w1, n_w2, e_w1);

  graph_kernel<<<dim3(B_GR), dim3(256), 0, stream>>>(
      c1_b, c2_as, c2_ad, c2_b, s_b1, s_w2, s_b2,
      n_b1, n_b2, e_b1, e_w2, e_b2, x, ei, ea, nedg, out);
}